// Round 10
// baseline (229.469 us; speedup 1.0000x reference)
//
#include <hip/hip_runtime.h>
#include <cfloat>
#include <cmath>

#define NHEADS 3
#define HIDC   64
#define HCC    192   // NHEADS*HIDC
#define EMBC   128
#define WCOLS  384   // 2*HCC (Wl rows ++ Wr rows)
#define CAP    1280  // edge slots per 64-dst bucket (mean 1024, +8 sigma)
#define SPLIT  4     // edge blocks per bucket (partial facc + finalize merge)

typedef unsigned short bhalf;
typedef __attribute__((ext_vector_type(8))) short bf16x8;
typedef __attribute__((ext_vector_type(4))) float f32x4;
typedef __attribute__((ext_vector_type(2))) float f32x2;

__device__ __forceinline__ unsigned f2bf(float f) {   // RNE fp32 -> bf16 bits
  unsigned u = __float_as_uint(f);
  return (u + 0x7FFFu + ((u >> 16) & 1u)) >> 16;
}

// ---- prep: Wb bf16[384][128]; vh[3][128]; ch[3]; b16=16*bias[384];
//            We16=16*We[192]; att16=att/16[192]; cur[] bucket bases; sumexp=0.
// Scale trick: store fp8 of 16*x (leakyrelu positively homogeneous; 1/16
// folded into att16).
__global__ __launch_bounds__(256) void prep_kernel(
    const float* __restrict__ Wl, const float* __restrict__ Wr,
    const float* __restrict__ bl, const float* __restrict__ br,
    const float* __restrict__ Wout, const float* __restrict__ We,
    const float* __restrict__ att,
    bhalf* __restrict__ Wb, float* __restrict__ vh, float* __restrict__ b16,
    float* __restrict__ We16, float* __restrict__ att16, float* __restrict__ ch,
    unsigned* __restrict__ cur, float* __restrict__ sumexp, int NB)
{
  const int BASE = WCOLS * EMBC;
  int gt = blockIdx.x * 256 + threadIdx.x;
  if (gt < BASE) {                                      // Wb (bf16 RNE)
    int c = gt >> 7, k = gt & 127;
    float v = (c < HCC) ? Wl[c * EMBC + k] : Wr[(c - HCC) * EMBC + k];
    Wb[gt] = (bhalf)f2bf(v);
  } else if (gt < BASE + 384) {                         // vh (3*128, fp32 value path)
    int i = gt - BASE;
    int h = i >> 7, k = i & 127;
    float s = 0.f;
    for (int c = 0; c < HIDC; ++c)
      s += Wout[c] * Wl[(h * HIDC + c) * EMBC + k];
    vh[i] = s;
  } else if (gt < BASE + 768) {                         // b16 = 16*(bl++br)
    int c = gt - BASE - 384;
    b16[c] = 16.f * ((c < HCC) ? bl[c] : br[c - HCC]);
  } else if (gt < BASE + 960) {                         // We16
    int c = gt - BASE - 768;
    We16[c] = 16.f * We[c];
  } else if (gt < BASE + 1152) {                        // att16
    int c = gt - BASE - 960;
    att16[c] = att[c] * (1.f / 16.f);
  } else if (gt < BASE + 1155) {                        // ch
    int h = gt - BASE - 1152;
    float s = 0.f;
    for (int c = 0; c < HIDC; ++c) s += bl[h * HIDC + c] * Wout[c];
    ch[h] = s;
  } else if (gt < BASE + 1155 + NB) {                   // bucket append cursors
    int b = gt - BASE - 1155;
    cur[b * 16] = (unsigned)(b * CAP);                  // 64B-padded counters
  } else if (gt == BASE + 1155 + NB) {
    *sumexp = 0.f;
  }
}

// ---- MFMA GEMM, column-split x2: block handles 64 nodes x 192 cols ----
// half=0 -> Wl/xl8 (+ fused pj), half=1 -> Wr/xr8.
// Operand swap: mfma(Wfrag, pefrag) -> D col(lane&15)=node, row(q*4+reg)=wcol;
// each lane's 4 accs = 4 consecutive wcols -> one fp8 dword, direct store.
__global__ __launch_bounds__(256, 4) void gemm_kernel(
    const float* __restrict__ pe, const bhalf* __restrict__ Wb,
    const float* __restrict__ b16, const float* __restrict__ vh,
    const float* __restrict__ ch,
    unsigned char* __restrict__ xl8, unsigned char* __restrict__ xr8,
    float* __restrict__ pj, int N)
{
  __shared__ bhalf Ws[192 * 64];   // 24576 B: 192 cols x one 64-k half, swizzled
  const int tid  = threadIdx.x;
  const int w    = tid >> 6;
  const int lane = tid & 63;
  const int m    = lane & 15;
  const int q    = lane >> 4;
  const int nb   = blockIdx.x >> 1;
  const int half = blockIdx.x & 1;
  const int n0   = nb * 64;
  const int node = n0 + w * 16 + m;
  const size_t prow = (size_t)(node < N ? node : N - 1) * EMBC;

  // pe fragments (B-operand): 8 k-elems/lane per 32-k tile; pj partials fp32
  bf16x8 pfrag[4];
  float pjp[3] = {0.f, 0.f, 0.f};
  #pragma unroll
  for (int kt = 0; kt < 4; ++kt) {
    const float* p = pe + prow + kt * 32 + q * 8;
    float4 x = *(const float4*)p;
    float4 y = *(const float4*)(p + 4);
    if (half == 0) {
      #pragma unroll
      for (int h = 0; h < 3; ++h) {
        const float* v = vh + h * EMBC + kt * 32 + q * 8;
        float4 va = *(const float4*)v;
        float4 vb = *(const float4*)(v + 4);
        pjp[h] += x.x*va.x + x.y*va.y + x.z*va.z + x.w*va.w
                + y.x*vb.x + y.y*vb.y + y.z*vb.z + y.w*vb.w;
      }
    }
    union { bf16x8 v; unsigned u[4]; } uu;   // trunc-pack pe -> bf16
    uu.u[0] = (__float_as_uint(x.x) >> 16) | (__float_as_uint(x.y) & 0xFFFF0000u);
    uu.u[1] = (__float_as_uint(x.z) >> 16) | (__float_as_uint(x.w) & 0xFFFF0000u);
    uu.u[2] = (__float_as_uint(y.x) >> 16) | (__float_as_uint(y.y) & 0xFFFF0000u);
    uu.u[3] = (__float_as_uint(y.z) >> 16) | (__float_as_uint(y.w) & 0xFFFF0000u);
    pfrag[kt] = uu.v;
  }

  f32x4 acc[12];
  #pragma unroll
  for (int t = 0; t < 12; ++t) acc[t] = (f32x4){0.f, 0.f, 0.f, 0.f};

  for (int kh = 0; kh < 2; ++kh) {
    __syncthreads();                         // protect Ws reuse
    for (int f = tid; f < 192 * 8; f += 256) {     // stage 64-k half, coalesced
      int cc = f >> 3, s = f & 7;                  // s: 16B slot (8 bf16)
      uint4 v = *(const uint4*)(Wb + (size_t)(half * HCC + cc) * EMBC + kh * 64 + s * 8);
      *(uint4*)(Ws + cc * 64 + ((s ^ (cc & 7)) * 8)) = v;
    }
    __syncthreads();
    #pragma unroll
    for (int kt2 = 0; kt2 < 2; ++kt2) {
      #pragma unroll
      for (int t = 0; t < 12; ++t) {
        bf16x8 wf = *(const bf16x8*)(Ws + (t * 16 + m) * 64 + (((kt2 << 2) + q) ^ (m & 7)) * 8);
        acc[t] = __builtin_amdgcn_mfma_f32_16x16x32_bf16(wf, pfrag[kh * 2 + kt2], acc[t], 0, 0, 0);
      }
    }
  }

  // pj: reduce the 4 q-copies of node m (half 0 only)
  if (half == 0) {
    #pragma unroll
    for (int h = 0; h < 3; ++h) {
      pjp[h] += __shfl_xor(pjp[h], 16);
      pjp[h] += __shfl_xor(pjp[h], 32);
    }
    if (q == 0 && node < N) {
      pj[node * 3 + 0] = pjp[0] + ch[0];
      pj[node * 3 + 1] = pjp[1] + ch[1];
      pj[node * 3 + 2] = pjp[2] + ch[2];
    }
  }

  // epilogue: r = 16*acc + b16, fp8-pack 4 consecutive wcols, direct dword store
  if (node < N) {
    unsigned char* xo = half ? xr8 : xl8;
    #pragma unroll
    for (int t = 0; t < 12; ++t) {
      int col = t * 16 + q * 4;
      float4 b = *(const float4*)(b16 + half * HCC + col);
      float r0 = fmaf(acc[t][0], 16.f, b.x);
      float r1 = fmaf(acc[t][1], 16.f, b.y);
      float r2 = fmaf(acc[t][2], 16.f, b.z);
      float r3 = fmaf(acc[t][3], 16.f, b.w);
      int p = 0;
      p = __builtin_amdgcn_cvt_pk_fp8_f32(r0, r1, p, false);
      p = __builtin_amdgcn_cvt_pk_fp8_f32(r2, r3, p, true);
      *(unsigned*)(xo + (size_t)node * HCC + col) = (unsigned)p;
    }
  }
}

// ---- scatter: LDS-batched append into fixed-capacity dst buckets ----
#define SCH 1024
__global__ __launch_bounds__(256) void scatter_kernel(
    const int* __restrict__ ei, const float* __restrict__ ea,
    uint2* __restrict__ eb, unsigned* __restrict__ cur, int E, int NB)
{
  __shared__ unsigned lh[800], lbase[800];
  int tid = threadIdx.x;
  int base = blockIdx.x * SCH;
  for (int i = tid; i < NB; i += 256) lh[i] = 0;
  __syncthreads();
  #pragma unroll 4
  for (int i = 0; i < SCH / 256; ++i) {
    int e = base + i * 256 + tid;
    if (e < E) atomicAdd(&lh[ei[E + e] >> 6], 1u);
  }
  __syncthreads();
  for (int i = tid; i < NB; i += 256) {      // reserve global ranges
    unsigned c = lh[i];
    lbase[i] = c ? atomicAdd(&cur[i * 16], c) : 0u;
    lh[i] = 0;
  }
  __syncthreads();
  #pragma unroll 4
  for (int i = 0; i < SCH / 256; ++i) {
    int e = base + i * 256 + tid;
    if (e < E) {
      int src = ei[e], dst = ei[E + e];
      int bin = dst >> 6;
      unsigned slot = lbase[bin] + atomicAdd(&lh[bin], 1u);
      uint2 rec;
      rec.x = (unsigned)src | ((unsigned)dst << 16);   // N < 65536
      rec.y = __float_as_uint(ea[e]);
      eb[slot] = rec;
    }
  }
}

// ---- edge: SPLIT blocks per 64-dst bucket, each does a strided slice and
// writes PARTIAL facc (LDS-accumulated) to pfacc; no global atomics at all. ----
#define EPG 5
#define GPW 4
#define WCHUNK (EPG * GPW)     // 20 edges per wave iteration
__global__ __launch_bounds__(256, 4) void edge_kernel(
    const uint2* __restrict__ eb,
    const unsigned char* __restrict__ xl8, const unsigned char* __restrict__ xr8,
    const float* __restrict__ pj, const float* __restrict__ We16,
    const float* __restrict__ att16, const unsigned* __restrict__ cur,
    float* __restrict__ pfacc, int N)
{
  __shared__ uint4 xrs[64][13];   // owned dst rows (192 fp8), +1 pad: bank rotate
  __shared__ float facc[64][8];   // [local dst][0..2]=asum, [3..5]=numer (partial)
  const int tid  = threadIdx.x;
  const int w    = tid >> 6;
  const int lane = tid & 63;
  const int j = lane / 12;        // edge within group
  const int c = lane % 12;        // 16B chunk within row; head h = c>>2
  const bool act = lane < 60;
  const int blk    = blockIdx.x;
  const int bucket = blk >> 2;          // SPLIT = 4
  const int sl     = blk & 3;
  const int n0 = bucket << 6;
  const int start = bucket * CAP;
  const int end   = (int)cur[bucket * 16];   // start + count

  // stage owned xr rows + zero partial accumulators
  for (int i = tid; i < 768; i += 256) {
    int row = i / 12, slot = i % 12;
    int nn = n0 + row; if (nn >= N) nn = N - 1;
    xrs[row][slot] = *(const uint4*)(xr8 + (size_t)nn * HCC + slot * 16);
  }
  for (int i = tid; i < 512; i += 256) ((float*)facc)[i] = 0.f;

  float4 we[4], at[4];
  #pragma unroll
  for (int i = 0; i < 4; ++i) {
    we[i] = *(const float4*)(We16 + c * 16 + i * 4);
    at[i] = *(const float4*)(att16 + c * 16 + i * 4);
  }
  __syncthreads();

  const int gw = sl * 4 + w;            // global wave-slice id in [0,16)
  const int wstart = start + gw * WCHUNK;
  uint2 rec[GPW];
  #pragma unroll
  for (int g = 0; g < GPW; ++g) {
    int e = wstart + g * EPG + j;
    rec[g] = eb[e < end ? e : start];
  }

  for (int cb = wstart; cb < end; cb += 16 * WCHUNK) {
    int srcs[GPW], dsts[GPW]; float eavs[GPW];
    #pragma unroll
    for (int g = 0; g < GPW; ++g) {
      srcs[g] = (int)(rec[g].x & 0xFFFFu);
      dsts[g] = (int)(rec[g].x >> 16);
      eavs[g] = __uint_as_float(rec[g].y);
    }
    uint4 ul[GPW]; float pjv[GPW];
    #pragma unroll
    for (int g = 0; g < GPW; ++g)
      ul[g] = *(const uint4*)(xl8 + (size_t)srcs[g] * HCC + c * 16);
    #pragma unroll
    for (int g = 0; g < GPW; ++g)
      pjv[g] = pj[srcs[g] * 3 + (c >> 2)];
    uint4 ur[GPW];
    #pragma unroll
    for (int g = 0; g < GPW; ++g)
      ur[g] = xrs[dsts[g] & 63][c];

    // prefetch next iteration's records (independent of current compute)
    int nxt = cb + 16 * WCHUNK;
    #pragma unroll
    for (int g = 0; g < GPW; ++g) {
      int e = nxt + g * EPG + j;
      rec[g] = eb[(e < end) ? e : start];
    }

    #pragma unroll
    for (int g = 0; g < GPW; ++g) {
      const unsigned* ulp = &ul[g].x;
      const unsigned* urp = &ur[g].x;
      float sc = 0.f;
      #pragma unroll
      for (int i = 0; i < 4; ++i) {
        f32x2 l0 = __builtin_amdgcn_cvt_pk_f32_fp8(ulp[i], false);
        f32x2 l1 = __builtin_amdgcn_cvt_pk_f32_fp8(ulp[i], true);
        f32x2 r0 = __builtin_amdgcn_cvt_pk_f32_fp8(urp[i], false);
        f32x2 r1 = __builtin_amdgcn_cvt_pk_f32_fp8(urp[i], true);
        float m0 = l0.x + r0.x + eavs[g] * we[i].x;   // all values 16x-scaled
        float m1 = l0.y + r0.y + eavs[g] * we[i].y;
        float m2 = l1.x + r1.x + eavs[g] * we[i].z;
        float m3 = l1.y + r1.y + eavs[g] * we[i].w;
        sc += fmaxf(m0, 0.2f * m0) * at[i].x          // lrelu(16m)=16*lrelu(m)
            + fmaxf(m1, 0.2f * m1) * at[i].y
            + fmaxf(m2, 0.2f * m2) * at[i].z
            + fmaxf(m3, 0.2f * m3) * at[i].w;
      }
      sc += __shfl_xor(sc, 1);
      sc += __shfl_xor(sc, 2);
      bool ve = act && (cb + g * EPG + j < end);
      if (ve && (c & 3) == 0) {
        int h = c >> 2;
        int ld = dsts[g] & 63;
        float ex = __expf(sc);   // |a| small: max-free softmax safe
        atomicAdd(&facc[ld][h], ex);
        atomicAdd(&facc[ld][3 + h], ex * pjv[g]);
      }
    }
  }
  __syncthreads();

  // dump partial facc (coalesced, non-atomic)
  for (int i = tid; i < 512; i += 256)
    pfacc[(size_t)blk * 512 + i] = ((float*)facc)[i];
}

// ---- finalize: merge SPLIT partials per node, out[n]=exp(score), sumexp ----
__global__ __launch_bounds__(256) void finalize_kernel(
    const float* __restrict__ pfacc, float* __restrict__ sumexp,
    float* __restrict__ out, int N)
{
  int n = blockIdx.x * 256 + threadIdx.x;
  int t = threadIdx.x;
  float e = 0.f;
  if (n < N) {
    int bucket = n >> 6, ld = n & 63;
    float a0 = 0.f, a1 = 0.f, a2 = 0.f, m0 = 0.f, m1 = 0.f, m2 = 0.f;
    #pragma unroll
    for (int s = 0; s < SPLIT; ++s) {
      const float* p = pfacc + ((size_t)(bucket * SPLIT + s) * 512) + ld * 8;
      a0 += p[0]; a1 += p[1]; a2 += p[2];
      m0 += p[3]; m1 += p[4]; m2 += p[5];
    }
    float accs = 0.f;
    if (a0 > 0.f) accs += m0 / a0;   // empty segment -> 0
    if (a1 > 0.f) accs += m1 / a1;
    if (a2 > 0.f) accs += m2 / a2;
    e = expf(accs * (1.f / 3.f));
    out[n] = e;
  }
  __shared__ float red[256];
  red[t] = e;
  __syncthreads();
  for (int w = 128; w; w >>= 1) {
    if (t < w) red[t] += red[t + w];
    __syncthreads();
  }
  if (t == 0) atomicAdd(sumexp, red[0]);
}

__global__ __launch_bounds__(256) void norm_kernel(
    float* __restrict__ out, const float* __restrict__ sumexp, int N)
{
  int n = blockIdx.x * 256 + threadIdx.x;
  if (n < N) out[n] /= *sumexp;
}

extern "C" void kernel_launch(void* const* d_in, const int* in_sizes, int n_in,
                              void* d_out, int out_size, void* d_ws, size_t ws_size,
                              hipStream_t stream) {
  const int*   ei   = (const int*)  d_in[0];
  const float* ea   = (const float*)d_in[1];
  const float* pe   = (const float*)d_in[2];
  // d_in[3] sim_w: softmax over 1 element == 1.0 -> unused
  const float* Wl   = (const float*)d_in[4];
  const float* bl   = (const float*)d_in[5];
  const float* Wr   = (const float*)d_in[6];
  const float* br   = (const float*)d_in[7];
  const float* We   = (const float*)d_in[8];
  const float* att  = (const float*)d_in[9];
  // d_in[10] bias_gnn, d_in[12] bout: softmax-invariant constant shift, unused
  const float* Wout = (const float*)d_in[11];

  const int E = in_sizes[0] / 2;
  const int N = in_sizes[2] / EMBC;
  const int NB = (N + 63) >> 6;        // dst buckets of 64
  float* out = (float*)d_out;

  // workspace layout (16B-aligned sections)
  float* ws       = (float*)d_ws;
  float* sumexp   = ws;                               // 1 (+15 pad)
  unsigned* cur   = (unsigned*)(ws + 16);             // NB*16 (64B-padded)
  float* pj       = ws + 16 + (size_t)NB * 16;        // 3N
  float* vh       = pj + (size_t)3 * N;               // 384
  float* b16      = vh + 384;                         // 384
  float* We16     = b16 + 384;                        // 192
  float* att16   = We16 + 192;                        // 192
  float* ch       = att16 + 192;                      // 3 (+13 pad)
  bhalf* Wb       = (bhalf*)(ch + 16);                // 384*128 bf16
  unsigned char* xl8 = (unsigned char*)(Wb + (size_t)WCOLS * EMBC);  // N*192 fp8
  unsigned char* xr8 = xl8 + (size_t)N * HCC;                        // N*192 fp8
  uint2* eb       = (uint2*)(xr8 + (size_t)N * HCC);  // NB*CAP*8B bucketed edges
  float* pfacc    = (float*)(eb + (size_t)NB * CAP);  // NB*SPLIT*512 partials

  const int BASE = WCOLS * EMBC;
  prep_kernel  <<<(BASE + 1155 + NB + 1 + 255) / 256, 256, 0, stream>>>(
      Wl, Wr, bl, br, Wout, We, att, Wb, vh, b16, We16, att16, ch,
      cur, sumexp, NB);
  gemm_kernel  <<<NB * 2, 256, 0, stream>>>(pe, Wb, b16, vh, ch, xl8, xr8, pj, N);
  scatter_kernel<<<(E + SCH - 1) / SCH, 256, 0, stream>>>(ei, ea, eb, cur, E, NB);
  edge_kernel  <<<NB * SPLIT, 256, 0, stream>>>(eb, xl8, xr8, pj, We16, att16,
                                                cur, pfacc, N);
  finalize_kernel<<<(N + 255) / 256, 256, 0, stream>>>(pfacc, sumexp, out, N);
  norm_kernel  <<<(N + 255) / 256, 256, 0, stream>>>(out, sumexp, N);
}

// Round 12
// 211.877 us; speedup vs baseline: 1.0830x; 1.0830x over previous
//
#include <hip/hip_runtime.h>
#include <cfloat>
#include <cmath>

#define NHEADS 3
#define HIDC   64
#define HCC    192   // NHEADS*HIDC
#define EMBC   128
#define WCOLS  384   // 2*HCC (Wl rows ++ Wr rows)
#define CAP    1280  // edge slots per 64-dst bucket (mean 1024, +8 sigma)
#define SCH    4096  // edges per scatter block

typedef unsigned short bhalf;
typedef __fp16 half_t;
typedef __attribute__((ext_vector_type(2))) __fp16 h2;
typedef __attribute__((ext_vector_type(8))) short bf16x8;
typedef __attribute__((ext_vector_type(4))) float f32x4;

__device__ __forceinline__ unsigned f2bf(float f) {   // RNE fp32 -> bf16 bits
  unsigned u = __float_as_uint(f);
  return (u + 0x7FFFu + ((u >> 16) & 1u)) >> 16;
}
__device__ __forceinline__ unsigned h2bits(h2 v) {
  union { h2 h; unsigned u; } cv; cv.h = v; return cv.u;
}

// ---- prep: Wb bf16[384][128]; vh[3][128]; bfl[384]=bl++br; weh/atth fp16x2;
//            ch[3]; cur[] bucket cursors; sumexp=0. All natural scale now
//            (fp16 storage needs no 16x normalization trick).
__global__ __launch_bounds__(256) void prep_kernel(
    const float* __restrict__ Wl, const float* __restrict__ Wr,
    const float* __restrict__ bl, const float* __restrict__ br,
    const float* __restrict__ Wout, const float* __restrict__ We,
    const float* __restrict__ att,
    bhalf* __restrict__ Wb, float* __restrict__ vh, float* __restrict__ bfl,
    unsigned* __restrict__ weh, unsigned* __restrict__ atth,
    float* __restrict__ ch, unsigned* __restrict__ cur,
    float* __restrict__ sumexp, int NB)
{
  const int BASE = WCOLS * EMBC;
  int gt = blockIdx.x * 256 + threadIdx.x;
  if (gt < BASE) {                                      // Wb (bf16 RNE)
    int c = gt >> 7, k = gt & 127;
    float v = (c < HCC) ? Wl[c * EMBC + k] : Wr[(c - HCC) * EMBC + k];
    Wb[gt] = (bhalf)f2bf(v);
  } else if (gt < BASE + 384) {                         // vh (3*128, fp32 value path)
    int i = gt - BASE;
    int h = i >> 7, k = i & 127;
    float s = 0.f;
    for (int c = 0; c < HIDC; ++c)
      s += Wout[c] * Wl[(h * HIDC + c) * EMBC + k];
    vh[i] = s;
  } else if (gt < BASE + 768) {                         // bfl = bl++br
    int c = gt - BASE - 384;
    bfl[c] = (c < HCC) ? bl[c] : br[c - HCC];
  } else if (gt < BASE + 864) {                         // weh (96 x fp16x2)
    int i = gt - BASE - 768;
    weh[i] = h2bits(__builtin_amdgcn_cvt_pkrtz(We[2 * i], We[2 * i + 1]));
  } else if (gt < BASE + 960) {                         // atth
    int i = gt - BASE - 864;
    atth[i] = h2bits(__builtin_amdgcn_cvt_pkrtz(att[2 * i], att[2 * i + 1]));
  } else if (gt < BASE + 963) {                         // ch
    int h = gt - BASE - 960;
    float s = 0.f;
    for (int c = 0; c < HIDC; ++c) s += bl[h * HIDC + c] * Wout[c];
    ch[h] = s;
  } else if (gt < BASE + 963 + NB) {                    // bucket append cursors
    int b = gt - BASE - 963;
    cur[b * 16] = (unsigned)(b * CAP);                  // 64B-padded counters
  } else if (gt == BASE + 963 + NB) {
    *sumexp = 0.f;
  }
}

// ---- FUSED: MFMA GEMM (blocks < NB2) + edge scatter (rest). Independent
// workloads co-scheduled: scatter's VMEM hides under gemm's MFMA. ----
// gemm: operand swap mfma(Wfrag,pefrag) -> D col=node, row(q*4+reg)=wcol;
// 4 consecutive wcols/lane -> fp16 pack -> direct uint2 store. pj fused.
__global__ __launch_bounds__(256, 4) void gemmscatter_kernel(
    const float* __restrict__ pe, const bhalf* __restrict__ Wb,
    const float* __restrict__ bfl, const float* __restrict__ vh,
    const float* __restrict__ ch,
    half_t* __restrict__ xlh, half_t* __restrict__ xrh,
    float* __restrict__ pj, int N,
    const int* __restrict__ ei, const float* __restrict__ ea,
    uint2* __restrict__ eb, unsigned* __restrict__ cur, int E, int NB2)
{
  __shared__ union {
    bhalf Ws[192 * 64];                        // 24576 B gemm W tile
    struct { unsigned lh[800]; unsigned lbase[800]; } s;   // scatter hists
  } sm;
  const int tid = threadIdx.x;

  if ((int)blockIdx.x < NB2) {   // ================= GEMM =================
    const int w    = tid >> 6;
    const int lane = tid & 63;
    const int m    = lane & 15;
    const int q    = lane >> 4;
    const int nb   = blockIdx.x >> 1;
    const int half = blockIdx.x & 1;
    const int node = nb * 64 + w * 16 + m;
    const size_t prow = (size_t)(node < N ? node : N - 1) * EMBC;

    bf16x8 pfrag[4];
    float pjp[3] = {0.f, 0.f, 0.f};
    #pragma unroll
    for (int kt = 0; kt < 4; ++kt) {
      const float* p = pe + prow + kt * 32 + q * 8;
      float4 x = *(const float4*)p;
      float4 y = *(const float4*)(p + 4);
      if (half == 0) {
        #pragma unroll
        for (int h = 0; h < 3; ++h) {
          const float* v = vh + h * EMBC + kt * 32 + q * 8;
          float4 va = *(const float4*)v;
          float4 vb = *(const float4*)(v + 4);
          pjp[h] += x.x*va.x + x.y*va.y + x.z*va.z + x.w*va.w
                  + y.x*vb.x + y.y*vb.y + y.z*vb.z + y.w*vb.w;
        }
      }
      union { bf16x8 v; unsigned u[4]; } uu;   // trunc-pack pe -> bf16
      uu.u[0] = (__float_as_uint(x.x) >> 16) | (__float_as_uint(x.y) & 0xFFFF0000u);
      uu.u[1] = (__float_as_uint(x.z) >> 16) | (__float_as_uint(x.w) & 0xFFFF0000u);
      uu.u[2] = (__float_as_uint(y.x) >> 16) | (__float_as_uint(y.y) & 0xFFFF0000u);
      uu.u[3] = (__float_as_uint(y.z) >> 16) | (__float_as_uint(y.w) & 0xFFFF0000u);
      pfrag[kt] = uu.v;
    }

    f32x4 acc[12];
    #pragma unroll
    for (int t = 0; t < 12; ++t) acc[t] = (f32x4){0.f, 0.f, 0.f, 0.f};

    for (int kh = 0; kh < 2; ++kh) {
      __syncthreads();
      for (int f = tid; f < 192 * 8; f += 256) {     // stage 64-k half
        int cc = f >> 3, s = f & 7;
        uint4 v = *(const uint4*)(Wb + (size_t)(half * HCC + cc) * EMBC + kh * 64 + s * 8);
        *(uint4*)(sm.Ws + cc * 64 + ((s ^ (cc & 7)) * 8)) = v;
      }
      __syncthreads();
      #pragma unroll
      for (int kt2 = 0; kt2 < 2; ++kt2) {
        #pragma unroll
        for (int t = 0; t < 12; ++t) {
          bf16x8 wf = *(const bf16x8*)(sm.Ws + (t * 16 + m) * 64 + (((kt2 << 2) + q) ^ (m & 7)) * 8);
          acc[t] = __builtin_amdgcn_mfma_f32_16x16x32_bf16(wf, pfrag[kh * 2 + kt2], acc[t], 0, 0, 0);
        }
      }
    }

    if (half == 0) {   // pj: reduce the 4 q-copies of node m
      #pragma unroll
      for (int h = 0; h < 3; ++h) {
        pjp[h] += __shfl_xor(pjp[h], 16);
        pjp[h] += __shfl_xor(pjp[h], 32);
      }
      if (q == 0 && node < N) {
        pj[node * 3 + 0] = pjp[0] + ch[0];
        pj[node * 3 + 1] = pjp[1] + ch[1];
        pj[node * 3 + 2] = pjp[2] + ch[2];
      }
    }

    if (node < N) {   // epilogue: +bias, fp16 pack, direct 8B store
      half_t* xo = half ? xrh : xlh;
      #pragma unroll
      for (int t = 0; t < 12; ++t) {
        int col = t * 16 + q * 4;
        float4 b = *(const float4*)(bfl + half * HCC + col);
        h2 pa = __builtin_amdgcn_cvt_pkrtz(acc[t][0] + b.x, acc[t][1] + b.y);
        h2 pb = __builtin_amdgcn_cvt_pkrtz(acc[t][2] + b.z, acc[t][3] + b.w);
        uint2 st; st.x = h2bits(pa); st.y = h2bits(pb);
        *(uint2*)(xo + (size_t)node * HCC + col) = st;
      }
    }
  } else {   // ================= SCATTER =================
    const int base = (blockIdx.x - NB2) * SCH;
    for (int i = tid; i < 800; i += 256) sm.s.lh[i] = 0;
    __syncthreads();
    #pragma unroll 4
    for (int i = 0; i < SCH / 256; ++i) {
      int e = base + i * 256 + tid;
      if (e < E) atomicAdd(&sm.s.lh[ei[E + e] >> 6], 1u);
    }
    __syncthreads();
    for (int i = tid; i < 800; i += 256) {      // reserve global ranges
      unsigned c = sm.s.lh[i];
      sm.s.lbase[i] = c ? atomicAdd(&cur[i * 16], c) : 0u;
      sm.s.lh[i] = 0;
    }
    __syncthreads();
    #pragma unroll 4
    for (int i = 0; i < SCH / 256; ++i) {
      int e = base + i * 256 + tid;
      if (e < E) {
        int src = ei[e], dst = ei[E + e];
        int bin = dst >> 6;
        unsigned slot = sm.s.lbase[bin] + atomicAdd(&sm.s.lh[bin], 1u);
        uint2 rec;
        rec.x = (unsigned)src | ((unsigned)dst << 16);   // N < 65536
        rec.y = __float_as_uint(ea[e]);
        eb[slot] = rec;
      }
    }
  }
}

// ---- edge+reduce: block owns dsts [64b,64b+64). fp16 rows: packed-half2
// MLP with v_dot2_f32_f16, xr in LDS, LDS accumulation, direct out. ----
#define EPG 5
#define GPW 4
#define WCHUNK (EPG * GPW)     // 20 edges per wave iteration
__global__ __launch_bounds__(512, 4) void edge_kernel(
    const uint2* __restrict__ eb,
    const half_t* __restrict__ xlh, const half_t* __restrict__ xrh,
    const float* __restrict__ pj, const unsigned* __restrict__ weh,
    const unsigned* __restrict__ atth, const unsigned* __restrict__ cur,
    float* __restrict__ sumexp, float* __restrict__ out, int N)
{
  __shared__ uint4 xrs[64][25];   // owned dst rows (384 B = 24 slots, +1 pad)
  __shared__ float facc[64][8];   // [local dst][0..2]=asum, [3..5]=numer
  const int tid  = threadIdx.x;
  const int w    = tid >> 6;
  const int lane = tid & 63;
  const int j = lane / 12;        // edge within group
  const int c = lane % 12;        // 32B chunk within row; head h = c>>2
  const bool act = lane < 60;
  const int b = blockIdx.x;
  const int n0 = b << 6;
  const int start = b * CAP;
  const int end   = (int)cur[b * 16];   // start + count

  // stage owned xr rows + zero accumulators
  for (int i = tid; i < 64 * 24; i += 512) {
    int row = i / 24, sl = i % 24;
    int nn = n0 + row; if (nn >= N) nn = N - 1;
    xrs[row][sl] = *(const uint4*)(xrh + (size_t)nn * HCC + sl * 8);
  }
  if (tid < 512) ((float*)facc)[tid] = 0.f;

  // per-lane constant slices: 8 h2 each of We and att
  union U8 { uint4 u[2]; h2 h[8]; };
  U8 we, at;
  we.u[0] = *(const uint4*)(weh + c * 8);
  we.u[1] = *(const uint4*)(weh + c * 8 + 4);
  at.u[0] = *(const uint4*)(atth + c * 8);
  at.u[1] = *(const uint4*)(atth + c * 8 + 4);
  const h2 c02 = {(__fp16)0.2f, (__fp16)0.2f};
  __syncthreads();

  const int wstart = start + w * WCHUNK;
  uint2 rec[GPW];
  #pragma unroll
  for (int g = 0; g < GPW; ++g) {
    int e = wstart + g * EPG + j;
    rec[g] = eb[e < end ? e : start];
  }

  for (int cb = wstart; cb < end; cb += 8 * WCHUNK) {
    int srcs[GPW], dsts[GPW]; float eavs[GPW];
    #pragma unroll
    for (int g = 0; g < GPW; ++g) {
      srcs[g] = (int)(rec[g].x & 0xFFFFu);
      dsts[g] = (int)(rec[g].x >> 16);
      eavs[g] = __uint_as_float(rec[g].y);
    }
    union U8x { uint4 u[2]; h2 h[8]; };
    U8x ul[GPW]; float pjv[GPW];
    #pragma unroll
    for (int g = 0; g < GPW; ++g) {
      const half_t* rp = xlh + (size_t)srcs[g] * HCC + c * 16;
      ul[g].u[0] = ((const uint4*)rp)[0];
      ul[g].u[1] = ((const uint4*)rp)[1];
    }
    #pragma unroll
    for (int g = 0; g < GPW; ++g)
      pjv[g] = pj[srcs[g] * 3 + (c >> 2)];

    // prefetch next iteration's records
    int nxt = cb + 8 * WCHUNK;
    #pragma unroll
    for (int g = 0; g < GPW; ++g) {
      int e = nxt + g * EPG + j;
      rec[g] = eb[(e < end) ? e : start];
    }

    #pragma unroll
    for (int g = 0; g < GPW; ++g) {
      int ld = dsts[g] & 63;
      U8x ur;
      ur.u[0] = xrs[ld][c * 2];
      ur.u[1] = xrs[ld][c * 2 + 1];
      h2 eav2 = __builtin_amdgcn_cvt_pkrtz(eavs[g], eavs[g]);
      float sc = 0.f;
      #pragma unroll
      for (int i = 0; i < 8; ++i) {
        h2 m  = ul[g].h[i] + ur.h[i] + eav2 * we.h[i];   // pk_add + pk_fma
        h2 lr = __builtin_elementwise_max(m, m * c02);    // pk_mul + pk_max
        sc = __builtin_amdgcn_fdot2(lr, at.h[i], sc, false);
      }
      sc += __shfl_xor(sc, 1);
      sc += __shfl_xor(sc, 2);
      bool ve = act && (cb + g * EPG + j < end);
      if (ve && (c & 3) == 0) {
        int h = c >> 2;
        float ex = __expf(sc);   // |a| small: max-free softmax safe
        atomicAdd(&facc[ld][h], ex);
        atomicAdd(&facc[ld][3 + h], ex * pjv[g]);
      }
    }
  }
  __syncthreads();

  if (tid < 64) {   // wave 0: finalize 64 dsts, one global atomic per block
    int n = n0 + tid;
    float e = 0.f;
    if (n < N) {
      float accs = 0.f;
      #pragma unroll
      for (int h = 0; h < 3; ++h) {
        float d = facc[tid][h];
        if (d > 0.f) accs += facc[tid][3 + h] / d;   // empty segment -> 0
      }
      e = expf(accs * (1.f / 3.f));
      out[n] = e;
    }
    #pragma unroll
    for (int o = 32; o; o >>= 1) e += __shfl_xor(e, o);
    if (tid == 0) atomicAdd(sumexp, e);
  }
}

__global__ __launch_bounds__(256) void norm_kernel(
    float* __restrict__ out, const float* __restrict__ sumexp, int N)
{
  int n = blockIdx.x * 256 + threadIdx.x;
  if (n < N) out[n] /= *sumexp;
}

extern "C" void kernel_launch(void* const* d_in, const int* in_sizes, int n_in,
                              void* d_out, int out_size, void* d_ws, size_t ws_size,
                              hipStream_t stream) {
  const int*   ei   = (const int*)  d_in[0];
  const float* ea   = (const float*)d_in[1];
  const float* pe   = (const float*)d_in[2];
  // d_in[3] sim_w: softmax over 1 element == 1.0 -> unused
  const float* Wl   = (const float*)d_in[4];
  const float* bl   = (const float*)d_in[5];
  const float* Wr   = (const float*)d_in[6];
  const float* br   = (const float*)d_in[7];
  const float* We   = (const float*)d_in[8];
  const float* att  = (const float*)d_in[9];
  // d_in[10] bias_gnn, d_in[12] bout: softmax-invariant constant shift, unused
  const float* Wout = (const float*)d_in[11];

  const int E = in_sizes[0] / 2;
  const int N = in_sizes[2] / EMBC;
  const int NB = (N + 63) >> 6;        // dst buckets of 64
  float* out = (float*)d_out;

  // workspace layout (16B-aligned sections)
  float* ws       = (float*)d_ws;
  float* sumexp   = ws;                               // 1 (+15 pad)
  unsigned* cur   = (unsigned*)(ws + 16);             // NB*16 (64B-padded)
  float* pj       = ws + 16 + (size_t)NB * 16;        // 3N
  float* vh       = pj + (size_t)3 * N;               // 384
  float* bfl      = vh + 384;                         // 384
  unsigned* weh   = (unsigned*)(bfl + 384);           // 96
  unsigned* atth  = weh + 96;                         // 96
  float* ch       = (float*)(atth + 96);              // 3 (+13 pad)
  bhalf* Wb       = (bhalf*)(ch + 16);                // 384*128 bf16
  half_t* xlh     = (half_t*)(Wb + (size_t)WCOLS * EMBC);  // N*192 fp16
  half_t* xrh     = xlh + (size_t)N * HCC;                 // N*192 fp16
  uint2* eb       = (uint2*)(xrh + (size_t)N * HCC);  // NB*CAP*8B bucketed edges

  const int BASE = WCOLS * EMBC;
  const int NB2 = NB * 2;
  const int NSC = (E + SCH - 1) / SCH;
  prep_kernel<<<(BASE + 963 + NB + 1 + 255) / 256, 256, 0, stream>>>(
      Wl, Wr, bl, br, Wout, We, att, Wb, vh, bfl, weh, atth, ch,
      cur, sumexp, NB);
  gemmscatter_kernel<<<NB2 + NSC, 256, 0, stream>>>(
      pe, Wb, bfl, vh, ch, xlh, xrh, pj, N, ei, ea, eb, cur, E, NB2);
  edge_kernel<<<NB, 512, 0, stream>>>(eb, xlh, xrh, pj, weh, atth, cur,
                                      sumexp, out, N);
  norm_kernel<<<(N + 255) / 256, 256, 0, stream>>>(out, sumexp, N);
}

// Round 13
// 190.686 us; speedup vs baseline: 1.2034x; 1.1111x over previous
//
#include <hip/hip_runtime.h>
#include <cfloat>
#include <cmath>

#define NHEADS 3
#define HIDC   64
#define HCC    192   // NHEADS*HIDC
#define EMBC   128
#define WCOLS  384   // 2*HCC (Wl rows ++ Wr rows)
#define CAP    1280  // edge slots per 64-dst bucket (mean 1024, +8 sigma)
#define SCH    4096  // edges per scatter block
#define SPLIT  2     // edge blocks per bucket (partial facc + finalize)

typedef unsigned short bhalf;
typedef __fp16 half_t;
typedef __attribute__((ext_vector_type(2))) __fp16 h2;
typedef __attribute__((ext_vector_type(8))) short bf16x8;
typedef __attribute__((ext_vector_type(4))) float f32x4;
typedef __attribute__((ext_vector_type(2))) float f32x2;

__device__ __forceinline__ unsigned f2bf(float f) {   // RNE fp32 -> bf16 bits
  unsigned u = __float_as_uint(f);
  return (u + 0x7FFFu + ((u >> 16) & 1u)) >> 16;
}
__device__ __forceinline__ unsigned h2bits(h2 v) {
  union { h2 h; unsigned u; } cv; cv.h = v; return cv.u;
}

// ---- prep: Wb bf16[384][128]; bfl[384]=bl++br; weh=pk16(16*We);
//            atth=pk16(att/16); cur[] bucket cursors; sumexp=0.
// 16x fp8 scale trick: store fp8 of 16*x (leakyrelu positively homogeneous;
// 1/16 folded into atth).
__global__ __launch_bounds__(256) void prep_kernel(
    const float* __restrict__ Wl, const float* __restrict__ Wr,
    const float* __restrict__ bl, const float* __restrict__ br,
    const float* __restrict__ We, const float* __restrict__ att,
    bhalf* __restrict__ Wb, float* __restrict__ bfl,
    unsigned* __restrict__ weh, unsigned* __restrict__ atth,
    unsigned* __restrict__ cur, float* __restrict__ sumexp, int NB)
{
  const int BASE = WCOLS * EMBC;
  int gt = blockIdx.x * 256 + threadIdx.x;
  if (gt < BASE) {                                      // Wb (bf16 RNE)
    int c = gt >> 7, k = gt & 127;
    float v = (c < HCC) ? Wl[c * EMBC + k] : Wr[(c - HCC) * EMBC + k];
    Wb[gt] = (bhalf)f2bf(v);
  } else if (gt < BASE + 384) {                         // bfl = bl++br
    int c = gt - BASE;
    bfl[c] = (c < HCC) ? bl[c] : br[c - HCC];
  } else if (gt < BASE + 480) {                         // weh (96 x fp16x2 of 16*We)
    int i = gt - BASE - 384;
    weh[i] = h2bits(__builtin_amdgcn_cvt_pkrtz(16.f * We[2 * i], 16.f * We[2 * i + 1]));
  } else if (gt < BASE + 576) {                         // atth (att/16)
    int i = gt - BASE - 480;
    atth[i] = h2bits(__builtin_amdgcn_cvt_pkrtz(att[2 * i] * (1.f / 16.f),
                                                att[2 * i + 1] * (1.f / 16.f)));
  } else if (gt < BASE + 576 + NB) {                    // bucket append cursors
    int b = gt - BASE - 576;
    cur[b * 16] = (unsigned)(b * CAP);                  // 64B-padded counters
  } else if (gt == BASE + 576 + NB) {
    *sumexp = 0.f;
  }
}

// ---- FUSED: edge scatter (blocks < NSC, FIRST so they overlap) + MFMA GEMM.
// gemm: operand swap mfma(Wfrag,pefrag) -> D col=node, row(q*4+reg)=wcol;
// 4 consecutive wcols/lane -> fp8(16x) pack -> direct dword store.
// pj computed IN-EPILOGUE from (acc+bias)·Wout (exact fp32 value path).
__global__ __launch_bounds__(256, 4) void gemmscatter_kernel(
    const float* __restrict__ pe, const bhalf* __restrict__ Wb,
    const float* __restrict__ bfl, const float* __restrict__ Wout,
    unsigned char* __restrict__ xl8, unsigned char* __restrict__ xr8,
    float* __restrict__ pj, int N,
    const int* __restrict__ ei, const float* __restrict__ ea,
    uint2* __restrict__ eb, unsigned* __restrict__ cur, int E, int NSC)
{
  __shared__ union {
    bhalf Ws[192 * 64];                        // 24576 B gemm W tile
    struct { unsigned lh[800]; unsigned lbase[800]; } s;   // scatter hists
  } sm;
  const int tid = threadIdx.x;

  if ((int)blockIdx.x < NSC) {   // ============ SCATTER (dispatched first) ============
    const int base = blockIdx.x * SCH;
    for (int i = tid; i < 800; i += 256) sm.s.lh[i] = 0;
    __syncthreads();
    #pragma unroll 4
    for (int i = 0; i < SCH / 256; ++i) {
      int e = base + i * 256 + tid;
      if (e < E) atomicAdd(&sm.s.lh[ei[E + e] >> 6], 1u);
    }
    __syncthreads();
    for (int i = tid; i < 800; i += 256) {      // reserve global ranges
      unsigned c = sm.s.lh[i];
      sm.s.lbase[i] = c ? atomicAdd(&cur[i * 16], c) : 0u;
      sm.s.lh[i] = 0;
    }
    __syncthreads();
    #pragma unroll 4
    for (int i = 0; i < SCH / 256; ++i) {
      int e = base + i * 256 + tid;
      if (e < E) {
        int src = ei[e], dst = ei[E + e];
        int bin = dst >> 6;
        unsigned slot = sm.s.lbase[bin] + atomicAdd(&sm.s.lh[bin], 1u);
        uint2 rec;
        rec.x = (unsigned)src | ((unsigned)dst << 16);   // N < 65536
        rec.y = __float_as_uint(ea[e]);
        eb[slot] = rec;
      }
    }
  } else {   // ================= GEMM =================
    const int bid  = blockIdx.x - NSC;
    const int w    = tid >> 6;
    const int lane = tid & 63;
    const int m    = lane & 15;
    const int q    = lane >> 4;
    const int nb   = bid >> 1;
    const int half = bid & 1;
    const int node = nb * 64 + w * 16 + m;
    const size_t prow = (size_t)(node < N ? node : N - 1) * EMBC;

    bf16x8 pfrag[4];
    #pragma unroll
    for (int kt = 0; kt < 4; ++kt) {
      const float* p = pe + prow + kt * 32 + q * 8;
      float4 x = *(const float4*)p;
      float4 y = *(const float4*)(p + 4);
      union { bf16x8 v; unsigned u[4]; } uu;   // trunc-pack pe -> bf16
      uu.u[0] = (__float_as_uint(x.x) >> 16) | (__float_as_uint(x.y) & 0xFFFF0000u);
      uu.u[1] = (__float_as_uint(x.z) >> 16) | (__float_as_uint(x.w) & 0xFFFF0000u);
      uu.u[2] = (__float_as_uint(y.x) >> 16) | (__float_as_uint(y.y) & 0xFFFF0000u);
      uu.u[3] = (__float_as_uint(y.z) >> 16) | (__float_as_uint(y.w) & 0xFFFF0000u);
      pfrag[kt] = uu.v;
    }

    f32x4 acc[12];
    #pragma unroll
    for (int t = 0; t < 12; ++t) acc[t] = (f32x4){0.f, 0.f, 0.f, 0.f};

    for (int kh = 0; kh < 2; ++kh) {
      __syncthreads();
      for (int f = tid; f < 192 * 8; f += 256) {     // stage 64-k half
        int cc = f >> 3, s = f & 7;
        uint4 v = *(const uint4*)(Wb + (size_t)(half * HCC + cc) * EMBC + kh * 64 + s * 8);
        *(uint4*)(sm.Ws + cc * 64 + ((s ^ (cc & 7)) * 8)) = v;
      }
      __syncthreads();
      #pragma unroll
      for (int kt2 = 0; kt2 < 2; ++kt2) {
        #pragma unroll
        for (int t = 0; t < 12; ++t) {
          bf16x8 wf = *(const bf16x8*)(sm.Ws + (t * 16 + m) * 64 + (((kt2 << 2) + q) ^ (m & 7)) * 8);
          acc[t] = __builtin_amdgcn_mfma_f32_16x16x32_bf16(wf, pfrag[kh * 2 + kt2], acc[t], 0, 0, 0);
        }
      }
    }

    // epilogue: rr = acc + bias; pj partial (half 0) = rr·Wout; fp8-pack 16*rr
    float4 wo4[4];
    #pragma unroll
    for (int tt = 0; tt < 4; ++tt)
      wo4[tt] = *(const float4*)(Wout + tt * 16 + q * 4);
    float pjp[3] = {0.f, 0.f, 0.f};
    unsigned char* xo = half ? xr8 : xl8;
    #pragma unroll
    for (int t = 0; t < 12; ++t) {
      int col = t * 16 + q * 4;
      float4 b = *(const float4*)(bfl + half * HCC + col);
      float r0 = acc[t][0] + b.x;
      float r1 = acc[t][1] + b.y;
      float r2 = acc[t][2] + b.z;
      float r3 = acc[t][3] + b.w;
      if (half == 0) {
        float4 wo = wo4[t & 3];
        pjp[t >> 2] += r0 * wo.x + r1 * wo.y + r2 * wo.z + r3 * wo.w;
      }
      if (node < N) {
        int p = 0;
        p = __builtin_amdgcn_cvt_pk_fp8_f32(16.f * r0, 16.f * r1, p, false);
        p = __builtin_amdgcn_cvt_pk_fp8_f32(16.f * r2, 16.f * r3, p, true);
        *(unsigned*)(xo + (size_t)node * HCC + col) = (unsigned)p;
      }
    }
    if (half == 0) {   // reduce pj over the 4 q-copies of node m
      #pragma unroll
      for (int h = 0; h < 3; ++h) {
        pjp[h] += __shfl_xor(pjp[h], 16);
        pjp[h] += __shfl_xor(pjp[h], 32);
      }
      if (q == 0 && node < N) {
        pj[node * 3 + 0] = pjp[0];
        pj[node * 3 + 1] = pjp[1];
        pj[node * 3 + 2] = pjp[2];
      }
    }
  }
}

// ---- edge: SPLIT blocks per 64-dst bucket; fp8 gathers (no xr staging —
// dst rows are L1-hot), packed-fp16 MLP, LDS partial facc -> pfacc dump. ----
#define EPG 5
#define GPW 4
#define WCHUNK (EPG * GPW)     // 20 edges per wave iteration
__global__ __launch_bounds__(256, 4) void edge_kernel(
    const uint2* __restrict__ eb,
    const unsigned char* __restrict__ xl8, const unsigned char* __restrict__ xr8,
    const float* __restrict__ pj, const unsigned* __restrict__ weh,
    const unsigned* __restrict__ atth, const unsigned* __restrict__ cur,
    float* __restrict__ pfacc, int N)
{
  __shared__ float facc[64][8];   // [local dst][0..2]=asum, [3..5]=numer
  const int tid  = threadIdx.x;
  const int w    = tid >> 6;
  const int lane = tid & 63;
  const int j = lane / 12;        // edge within group
  const int c = lane % 12;        // 16B chunk within row; head h = c>>2
  const bool act = lane < 60;
  const int cc = act ? c : 0;
  const int blk    = blockIdx.x;
  const int bucket = blk >> 1;    // SPLIT = 2
  const int sl     = blk & 1;
  const int start = bucket * CAP;
  const int end   = (int)cur[bucket * 16];   // start + count

  for (int i = tid; i < 512; i += 256) ((float*)facc)[i] = 0.f;

  union U8 { uint4 u[2]; h2 h[8]; };
  U8 we, at;
  we.u[0] = *(const uint4*)(weh + cc * 8);
  we.u[1] = *(const uint4*)(weh + cc * 8 + 4);
  at.u[0] = *(const uint4*)(atth + cc * 8);
  at.u[1] = *(const uint4*)(atth + cc * 8 + 4);
  const h2 c02 = {(__fp16)0.2f, (__fp16)0.2f};
  __syncthreads();

  const int gw = sl * 4 + w;      // wave-slice id in [0,8)
  const int wstart = start + gw * WCHUNK;
  uint2 rec[GPW];
  #pragma unroll
  for (int g = 0; g < GPW; ++g) {
    int e = wstart + g * EPG + j;
    rec[g] = eb[e < end ? e : start];
  }

  for (int cb = wstart; cb < end; cb += 8 * WCHUNK) {
    int srcs[GPW], dsts[GPW]; float eavs[GPW];
    #pragma unroll
    for (int g = 0; g < GPW; ++g) {
      srcs[g] = (int)(rec[g].x & 0xFFFFu);
      dsts[g] = (int)(rec[g].x >> 16);
      eavs[g] = __uint_as_float(rec[g].y);
    }
    uint4 ul[GPW], ur[GPW]; float pjv[GPW];
    #pragma unroll
    for (int g = 0; g < GPW; ++g)
      ul[g] = *(const uint4*)(xl8 + (size_t)srcs[g] * HCC + cc * 16);
    #pragma unroll
    for (int g = 0; g < GPW; ++g)
      ur[g] = *(const uint4*)(xr8 + (size_t)dsts[g] * HCC + cc * 16);
    #pragma unroll
    for (int g = 0; g < GPW; ++g)
      pjv[g] = pj[srcs[g] * 3 + (c >> 2)];

    // prefetch next iteration's records
    int nxt = cb + 8 * WCHUNK;
    #pragma unroll
    for (int g = 0; g < GPW; ++g) {
      int e = nxt + g * EPG + j;
      rec[g] = eb[(e < end) ? e : start];
    }

    #pragma unroll
    for (int g = 0; g < GPW; ++g) {
      const unsigned* ulp = &ul[g].x;
      const unsigned* urp = &ur[g].x;
      h2 eav2 = __builtin_amdgcn_cvt_pkrtz(eavs[g], eavs[g]);
      float sc = 0.f;
      #pragma unroll
      for (int i = 0; i < 4; ++i) {   // 16 elems: fp8 -> h2 pairs -> pk math
        f32x2 la = __builtin_amdgcn_cvt_pk_f32_fp8(ulp[i], false);
        f32x2 lb = __builtin_amdgcn_cvt_pk_f32_fp8(ulp[i], true);
        f32x2 ra = __builtin_amdgcn_cvt_pk_f32_fp8(urp[i], false);
        f32x2 rb = __builtin_amdgcn_cvt_pk_f32_fp8(urp[i], true);
        h2 l0 = __builtin_amdgcn_cvt_pkrtz(la.x, la.y);
        h2 l1 = __builtin_amdgcn_cvt_pkrtz(lb.x, lb.y);
        h2 r0 = __builtin_amdgcn_cvt_pkrtz(ra.x, ra.y);
        h2 r1 = __builtin_amdgcn_cvt_pkrtz(rb.x, rb.y);
        h2 m0 = l0 + r0 + eav2 * we.h[2 * i];       // 16x-scaled throughout
        h2 m1 = l1 + r1 + eav2 * we.h[2 * i + 1];
        h2 q0 = __builtin_elementwise_max(m0, m0 * c02);  // lrelu(16m)=16*lrelu(m)
        h2 q1 = __builtin_elementwise_max(m1, m1 * c02);
        sc = __builtin_amdgcn_fdot2(q0, at.h[2 * i], sc, false);
        sc = __builtin_amdgcn_fdot2(q1, at.h[2 * i + 1], sc, false);
      }
      sc += __shfl_xor(sc, 1);
      sc += __shfl_xor(sc, 2);
      bool ve = act && (cb + g * EPG + j < end);
      if (ve && (c & 3) == 0) {
        int h = c >> 2;
        int ld = dsts[g] & 63;
        float ex = __expf(sc);   // |a| small: max-free softmax safe
        atomicAdd(&facc[ld][h], ex);
        atomicAdd(&facc[ld][3 + h], ex * pjv[g]);
      }
    }
  }
  __syncthreads();

  for (int i = tid; i < 512; i += 256)      // dump partials (non-atomic)
    pfacc[(size_t)blk * 512 + i] = ((float*)facc)[i];
}

// ---- finalize: merge SPLIT partials, out[n]=exp(score), block sumexp ----
__global__ __launch_bounds__(256) void finalize_kernel(
    const float* __restrict__ pfacc, float* __restrict__ sumexp,
    float* __restrict__ out, int N)
{
  int n = blockIdx.x * 256 + threadIdx.x;
  int t = threadIdx.x;
  float e = 0.f;
  if (n < N) {
    int bucket = n >> 6, ld = n & 63;
    float a0 = 0.f, a1 = 0.f, a2 = 0.f, m0 = 0.f, m1 = 0.f, m2 = 0.f;
    #pragma unroll
    for (int s = 0; s < SPLIT; ++s) {
      const float* p = pfacc + ((size_t)(bucket * SPLIT + s) * 512) + ld * 8;
      a0 += p[0]; a1 += p[1]; a2 += p[2];
      m0 += p[3]; m1 += p[4]; m2 += p[5];
    }
    float accs = 0.f;
    if (a0 > 0.f) accs += m0 / a0;   // empty segment -> 0 (matches ref)
    if (a1 > 0.f) accs += m1 / a1;
    if (a2 > 0.f) accs += m2 / a2;
    e = expf(accs * (1.f / 3.f));
    out[n] = e;
  }
  __shared__ float red[256];
  red[t] = e;
  __syncthreads();
  for (int w = 128; w; w >>= 1) {
    if (t < w) red[t] += red[t + w];
    __syncthreads();
  }
  if (t == 0) atomicAdd(sumexp, red[0]);
}

__global__ __launch_bounds__(256) void norm_kernel(
    float* __restrict__ out, const float* __restrict__ sumexp, int N)
{
  int n = blockIdx.x * 256 + threadIdx.x;
  if (n < N) out[n] /= *sumexp;
}

extern "C" void kernel_launch(void* const* d_in, const int* in_sizes, int n_in,
                              void* d_out, int out_size, void* d_ws, size_t ws_size,
                              hipStream_t stream) {
  const int*   ei   = (const int*)  d_in[0];
  const float* ea   = (const float*)d_in[1];
  const float* pe   = (const float*)d_in[2];
  // d_in[3] sim_w: softmax over 1 element == 1.0 -> unused
  const float* Wl   = (const float*)d_in[4];
  const float* bl   = (const float*)d_in[5];
  const float* Wr   = (const float*)d_in[6];
  const float* br   = (const float*)d_in[7];
  const float* We   = (const float*)d_in[8];
  const float* att  = (const float*)d_in[9];
  // d_in[10] bias_gnn, d_in[12] bout: softmax-invariant constant shift, unused
  const float* Wout = (const float*)d_in[11];

  const int E = in_sizes[0] / 2;
  const int N = in_sizes[2] / EMBC;
  const int NB = (N + 63) >> 6;        // dst buckets of 64
  float* out = (float*)d_out;

  // workspace layout (16B-aligned sections)
  float* ws       = (float*)d_ws;
  float* sumexp   = ws;                               // 1 (+15 pad)
  unsigned* cur   = (unsigned*)(ws + 16);             // NB*16 (64B-padded)
  float* pj       = ws + 16 + (size_t)NB * 16;        // 3N
  float* bfl      = pj + (size_t)3 * N;               // 384
  unsigned* weh   = (unsigned*)(bfl + 384);           // 96
  unsigned* atth  = weh + 96;                         // 96
  bhalf* Wb       = (bhalf*)(atth + 96);              // 384*128 bf16
  unsigned char* xl8 = (unsigned char*)(Wb + (size_t)WCOLS * EMBC);  // N*192 fp8
  unsigned char* xr8 = xl8 + (size_t)N * HCC;                        // N*192 fp8
  uint2* eb       = (uint2*)(xr8 + (size_t)N * HCC);  // NB*CAP*8B bucketed edges
  float* pfacc    = (float*)(eb + (size_t)NB * CAP);  // NB*SPLIT*512 partials

  const int BASE = WCOLS * EMBC;
  const int NSC = (E + SCH - 1) / SCH;
  prep_kernel<<<(BASE + 576 + NB + 1 + 255) / 256, 256, 0, stream>>>(
      Wl, Wr, bl, br, We, att, Wb, bfl, weh, atth, cur, sumexp, NB);
  gemmscatter_kernel<<<NSC + NB * 2, 256, 0, stream>>>(
      pe, Wb, bfl, Wout, xl8, xr8, pj, N, ei, ea, eb, cur, E, NSC);
  edge_kernel<<<NB * SPLIT, 256, 0, stream>>>(eb, xl8, xr8, pj, weh, atth,
                                              cur, pfacc, N);
  finalize_kernel<<<(N + 255) / 256, 256, 0, stream>>>(pfacc, sumexp, out, N);
  norm_kernel<<<(N + 255) / 256, 256, 0, stream>>>(out, sumexp, N);
}